// Round 9
// baseline (225.778 us; speedup 1.0000x reference)
//
#include <hip/hip_runtime.h>

#define NN 50000
#define EE 800000
#define NEG 0.2f
#define CAP 128    // per-wave LDS edge stash (deg ~Poisson(16), max ~45; fallback kept)
#define NBC 98     // coarse buckets of 512 nodes for CSR build
#define BSH2 9
#define CAPB 16384 // buf capacity per bucket (mean 8163 -> huge margin)
#define PCH 3125   // edges per k_part block (256 * 3125 == EE exactly)

typedef long long i64;
typedef unsigned int u32;
typedef unsigned short u16;
typedef __attribute__((ext_vector_type(8))) short bf16x8;
typedef __attribute__((ext_vector_type(4))) float f32x4;

static __device__ __forceinline__ float wave_max64(float v) {
#pragma unroll
  for (int m = 32; m >= 1; m >>= 1) v = fmaxf(v, __shfl_xor(v, m, 64));
  return v;
}
static __device__ __forceinline__ float wave_sum64(float v) {
#pragma unroll
  for (int m = 32; m >= 1; m >>= 1) v += __shfl_xor(v, m, 64);
  return v;
}

// bf16 helpers
static __device__ __forceinline__ u16 f2bf(float f) {
  u32 u = __float_as_uint(f);
  u += 0x7FFFu + ((u >> 16) & 1u);
  return (u16)(u >> 16);
}
static __device__ __forceinline__ float bflo(u32 v) { return __uint_as_float(v << 16); }
static __device__ __forceinline__ float bfhi(u32 v) { return __uint_as_float(v & 0xffff0000u); }
static __device__ __forceinline__ u32 pack2bf(float a, float b) {
  return (u32)f2bf(a) | ((u32)f2bf(b) << 16);
}
// accumulate 4 dwords (8 bf16) * scale into acc[8]
static __device__ __forceinline__ void fma8(float* acc, int4 v, float a) {
  acc[0] += bflo(v.x) * a; acc[1] += bfhi(v.x) * a;
  acc[2] += bflo(v.y) * a; acc[3] += bfhi(v.y) * a;
  acc[4] += bflo(v.z) * a; acc[5] += bfhi(v.z) * a;
  acc[6] += bflo(v.w) * a; acc[7] += bfhi(v.w) * a;
}

// ---- dtype probe + zero bucket counters ----------------------------------
__global__ void k_probe(const void* ei, int* flag, int* gcnt) {
  __shared__ int sbad[4];
  int t = threadIdx.x;
  if (t < NBC) gcnt[t] = 0;
  const i64* p = (const i64*)ei;
  i64 v = p[t];
  int bad = (v < 0 || v >= NN) ? 1 : 0;
  unsigned long long b = __ballot(bad);
  if ((t & 63) == 0) sbad[t >> 6] = (b != 0ULL);
  __syncthreads();
  if (t == 0) *flag = !(sbad[0] | sbad[1] | sbad[2] | sbad[3]);
}

static __device__ __forceinline__ int edge_at(const void* ei, int is64, int idx) {
  return is64 ? (int)((const i64*)ei)[idx] : ((const int*)ei)[idx];
}

// ---- pass 1: per-block LDS counting sort into 98 coarse buckets ----------
__global__ void k_part(const void* ei, const int* flag, int* gcnt, u32* buf) {
  __shared__ u32 lbuf[PCH];
  __shared__ int hist[128], offb[128], curb[128], gbase[128], sc[128];
  int t = threadIdx.x;
  int is64 = *flag;
  if (t < 128) { hist[t] = 0; curb[t] = 0; }
  __syncthreads();
  int lo = blockIdx.x * PCH;

  for (int e = lo + t; e < lo + PCH; e += 256)
    atomicAdd(&hist[edge_at(ei, is64, EE + e) >> BSH2], 1);
  __syncthreads();

  if (t < 128) sc[t] = hist[t];
  __syncthreads();
  for (int o = 1; o < 128; o <<= 1) {
    int v = (t >= o && t < 128) ? sc[t - o] : 0;
    __syncthreads();
    if (t < 128) sc[t] += v;
    __syncthreads();
  }
  if (t < 128) offb[t] = sc[t] - hist[t];
  __syncthreads();

  for (int e = lo + t; e < lo + PCH; e += 256) {
    int s = edge_at(ei, is64, e);
    int d = edge_at(ei, is64, EE + e);
    int b = d >> BSH2;
    u32 v = (u32)s | ((u32)(d & 511) << 16) | ((u32)b << 25);
    int p = atomicAdd(&curb[b], 1);
    lbuf[offb[b] + p] = v;
  }
  __syncthreads();

  if (t < 128) {
    int c = hist[t];
    gbase[t] = c ? atomicAdd(&gcnt[t], c) : 0;
  }
  __syncthreads();

  for (int i = t; i < PCH; i += 256) {
    u32 v = lbuf[i];
    int b = v >> 25;
    int pos = gbase[b] + (i - offb[b]);
    if (pos < CAPB) buf[(size_t)b * CAPB + pos] = v;
  }
}

// ---- pass 2: exclusive scan of bucket counts -----------------------------
__global__ void k_scanb(const int* gcnt, int* csrbase, int* rowp) {
  __shared__ int sc[128];
  int t = threadIdx.x;
  int c = (t < NBC) ? min(gcnt[t], CAPB) : 0;
  sc[t] = c;
  __syncthreads();
  for (int o = 1; o < 128; o <<= 1) {
    int v = (t >= o) ? sc[t - o] : 0;
    __syncthreads();
    sc[t] += v;
    __syncthreads();
  }
  if (t < NBC) csrbase[t] = sc[t] - c;
  if (t == 127) rowp[NN] = sc[127];
}

// ---- pass 3: per-bucket local sort -> rowp, dinv, csr --------------------
__global__ void k_csr2(const u32* __restrict__ buf, const int* __restrict__ gcnt,
                       const int* __restrict__ csrbase, int* __restrict__ rowp,
                       float* __restrict__ dinv, int* __restrict__ csr) {
  __shared__ int hist[512], offs[512], cur[512], sc[256];
  int b = blockIdx.x;
  int t = threadIdx.x;
  int cnt = min(gcnt[b], CAPB);
  const u32* mb = buf + (size_t)b * CAPB;
  int cbase = csrbase[b];
  int nbase = b << BSH2;
  int nn = min(512, NN - nbase);
  hist[t] = 0; hist[t + 256] = 0; cur[t] = 0; cur[t + 256] = 0;
  __syncthreads();
  for (int i = t; i < cnt; i += 256) atomicAdd(&hist[(mb[i] >> 16) & 511], 1);
  __syncthreads();
  int a0 = hist[2 * t], a1 = hist[2 * t + 1];
  sc[t] = a0 + a1;
  __syncthreads();
  for (int o = 1; o < 256; o <<= 1) {
    int v = (t >= o) ? sc[t - o] : 0;
    __syncthreads();
    sc[t] += v;
    __syncthreads();
  }
  int excl = sc[t] - (a0 + a1);
  offs[2 * t] = excl; offs[2 * t + 1] = excl + a0;
  __syncthreads();
  for (int i = t; i < nn; i += 256) {
    rowp[nbase + i] = cbase + offs[i];
    dinv[nbase + i] = rsqrtf((float)(hist[i] + 1));
  }
  for (int i = t; i < cnt; i += 256) {
    u32 v = mb[i];
    int dl = (v >> 16) & 511;
    int p = atomicAdd(&cur[dl], 1);
    csr[cbase + offs[dl] + p] = (int)(v & 0xFFFF);
  }
}

// ---- MFMA GEMM (as round 8) ----------------------------------------------
template <int K, int N, bool SRCF32, bool ATT, int NTH>
__global__ void k_mm(const void* __restrict__ Xsrc, const float* __restrict__ W,
                     const float* __restrict__ aw_s, const float* __restrict__ aw_d,
                     u16* __restrict__ Y, float* __restrict__ a_sv,
                     float* __restrict__ a_dv) {
  constexpr int BM = 64;
  constexpr int NT = N / 16;
  constexpr int KS = K / 32;
  __shared__ u16 Ab[BM * K];
  __shared__ u16 Wt[N * K];
  int t = threadIdx.x;
  int blockRow = blockIdx.x * BM;

  if (SRCF32) {
    const float4* Xq = (const float4*)Xsrc + (size_t)blockRow * (K / 4);
    for (int i = t; i < BM * K / 4; i += 256) {
      int r = (i * 4) / K;
      float4 v = (blockRow + r < NN) ? Xq[i] : make_float4(0.f, 0.f, 0.f, 0.f);
      ushort4 p = make_ushort4(f2bf(v.x), f2bf(v.y), f2bf(v.z), f2bf(v.w));
      int b = i * 8;
      *(ushort4*)((char*)Ab + (b ^ ((r & 7) << 4))) = p;
    }
  } else {
    const int4* Xq = (const int4*)Xsrc + (size_t)blockRow * (K / 8);
    for (int i = t; i < BM * K / 8; i += 256) {
      int r = (i * 8) / K;
      int4 v = (blockRow + r < NN) ? Xq[i] : make_int4(0, 0, 0, 0);
      int b = i * 16;
      *(int4*)((char*)Ab + (b ^ ((r & 7) << 4))) = v;
    }
  }
  for (int i = t; i < K * N; i += 256) {
    int k = i / N, n = i % N;
    int b = (n * K + k) * 2;
    *(u16*)((char*)Wt + (b ^ ((n & 7) << 4))) = f2bf(W[i]);
  }
  __syncthreads();

  int w = t >> 6, l = t & 63;
  int lr = l & 15, lg = l >> 4;
  int sw = (lr & 7) << 4;
  f32x4 acc[NT];
#pragma unroll
  for (int nt = 0; nt < NT; ++nt) acc[nt] = (f32x4)0.f;

#pragma unroll
  for (int ks = 0; ks < KS; ++ks) {
    int ar = 16 * w + lr;
    int ab = (ar * K + ks * 32 + lg * 8) * 2;
    bf16x8 af = *(bf16x8*)((char*)Ab + (ab ^ sw));
#pragma unroll
    for (int nt = 0; nt < NT; ++nt) {
      int bb = ((nt * 16 + lr) * K + ks * 32 + lg * 8) * 2;
      bf16x8 bfr = *(bf16x8*)((char*)Wt + (bb ^ sw));
      acc[nt] = __builtin_amdgcn_mfma_f32_16x16x32_bf16(af, bfr, acc[nt], 0, 0, 0);
    }
  }

#pragma unroll
  for (int j = 0; j < 4; ++j) {
    int row = blockRow + 16 * w + lg * 4 + j;
    if (row < NN) {
      u16* yr = Y + (size_t)row * N + lr;
#pragma unroll
      for (int nt = 0; nt < NT; ++nt) yr[nt * 16] = f2bf(acc[nt][j]);
    }
  }

  if (ATT) {
    float aws[NT], awd[NT];
#pragma unroll
    for (int nt = 0; nt < NT; ++nt) {
      aws[nt] = aw_s[nt * 16 + lr];
      awd[nt] = aw_d[nt * 16 + lr];
    }
#pragma unroll
    for (int j = 0; j < 4; ++j) {
      int row = blockRow + 16 * w + lg * 4 + j;
#pragma unroll
      for (int h = 0; h < 2; ++h) {
        float s = 0.f, d = 0.f;
#pragma unroll
        for (int q = 0; q < NTH; ++q) {
          int nt = h * NTH + q;
          s += acc[nt][j] * aws[nt];
          d += acc[nt][j] * awd[nt];
        }
#pragma unroll
        for (int mm = 8; mm >= 1; mm >>= 1) {
          s += __shfl_xor(s, mm, 64);
          d += __shfl_xor(d, mm, 64);
        }
        if (lr == 0 && row < NN) {
          a_sv[row * 2 + h] = s;
          a_dv[row * 2 + h] = d;
        }
      }
    }
  }
}

// ---- GCN aggregation: 8 lanes/row int4, 8 edges per wave-pass ------------
__global__ void k_gcn(const u16* __restrict__ g, const float* __restrict__ dinv,
                      const int* __restrict__ rowp, const int* __restrict__ csr,
                      const float* __restrict__ bias, u16* __restrict__ outb) {
  __shared__ int   s_src[4][CAP];
  __shared__ float s_wt[4][CAP];
  int wid = (blockIdx.x * blockDim.x + threadIdx.x) >> 6;
  int w = (threadIdx.x >> 6) & 3;
  int lane = threadIdx.x & 63;
  if (wid >= NN) return;
  float di = dinv[wid];
  int beg = rowp[wid], cnt = rowp[wid + 1] - beg;
  int tot = cnt + 1;                 // self loop at idx == cnt
  int c1 = min(tot, CAP);

  for (int idx = lane; idx < c1; idx += 64) {
    int s = (idx < cnt) ? csr[beg + idx] : wid;
    s_src[w][idx] = s;
    s_wt[w][idx]  = (idx < cnt) ? dinv[s] : di;
  }

  int gq = lane >> 3, q = lane & 7;
  const int4* g4 = (const int4*)g;   // 8 int4 per 64-feature row
  float acc[8] = {0.f, 0.f, 0.f, 0.f, 0.f, 0.f, 0.f, 0.f};
  for (int idx = gq; idx < c1; idx += 8) {
    int s = s_src[w][idx];
    float a = s_wt[w][idx];
    fma8(acc, g4[(size_t)s * 8 + q], a);
  }
  for (int idx = CAP + gq; idx < tot; idx += 8) {   // essentially never
    int s = (idx < cnt) ? csr[beg + idx] : wid;
    float a = (idx < cnt) ? dinv[s] : di;
    fma8(acc, g4[(size_t)s * 8 + q], a);
  }
#pragma unroll
  for (int j = 0; j < 8; ++j) {
    acc[j] += __shfl_xor(acc[j], 8, 64);
    acc[j] += __shfl_xor(acc[j], 16, 64);
    acc[j] += __shfl_xor(acc[j], 32, 64);
  }
  if (gq == 0) {   // lanes 0..7 write the full 128B row
    u32 o[4];
#pragma unroll
    for (int p = 0; p < 4; ++p) {
      float v0 = fmaxf(acc[2 * p] * di + bias[8 * q + 2 * p], 0.f);
      float v1 = fmaxf(acc[2 * p + 1] * di + bias[8 * q + 2 * p + 1], 0.f);
      o[p] = pack2bf(v0, v1);
    }
    ((int4*)outb)[(size_t)wid * 8 + q] = *(int4*)o;
  }
}

// ---- GAT layer 1: 16 lanes/row int4, 4 edges per wave-pass ---------------
__global__ void k_gat1(const u16* __restrict__ hg, const float* __restrict__ a_s,
                       const float* __restrict__ a_d, const int* __restrict__ rowp,
                       const int* __restrict__ csr, const float* __restrict__ bias,
                       u16* __restrict__ outb) {
  __shared__ int   s_src[4][CAP];
  __shared__ float s_x0[4][CAP];
  __shared__ float s_x1[4][CAP];
  int wid = (blockIdx.x * blockDim.x + threadIdx.x) >> 6;
  int w = (threadIdx.x >> 6) & 3;
  int lane = threadIdx.x & 63;
  if (wid >= NN) return;
  int beg = rowp[wid], cnt = rowp[wid + 1] - beg;
  int tot = cnt + 1;
  int c1 = min(tot, CAP);
  float ad0 = a_d[wid * 2], ad1 = a_d[wid * 2 + 1];
  float m0, m1, inv0, inv1;

  if (tot <= 64) {  // fast path: one edge per lane, straight-line softmax
    bool act = lane < tot;
    int s = (lane < cnt) ? csr[beg + lane] : wid;
    float e0 = -1e30f, e1 = -1e30f;
    if (act) {
      float2 av = ((const float2*)a_s)[s];
      e0 = av.x + ad0; e0 = e0 > 0.f ? e0 : NEG * e0;
      e1 = av.y + ad1; e1 = e1 > 0.f ? e1 : NEG * e1;
    }
    m0 = wave_max64(e0); m1 = wave_max64(e1);
    float x0 = act ? __expf(e0 - m0) : 0.f;
    float x1 = act ? __expf(e1 - m1) : 0.f;
    inv0 = 1.f / wave_sum64(x0); inv1 = 1.f / wave_sum64(x1);
    if (act) { s_src[w][lane] = s; s_x0[w][lane] = x0; s_x1[w][lane] = x1; }
  } else {  // generic fallback
    float mm0 = -1e30f, mm1 = -1e30f;
    for (int idx = lane; idx < tot; idx += 64) {
      int s = (idx < cnt) ? csr[beg + idx] : wid;
      float2 av = ((const float2*)a_s)[s];
      float e0 = av.x + ad0; e0 = e0 > 0.f ? e0 : NEG * e0;
      float e1 = av.y + ad1; e1 = e1 > 0.f ? e1 : NEG * e1;
      if (idx < CAP) { s_src[w][idx] = s; s_x0[w][idx] = e0; s_x1[w][idx] = e1; }
      mm0 = fmaxf(mm0, e0); mm1 = fmaxf(mm1, e1);
    }
    m0 = wave_max64(mm0); m1 = wave_max64(mm1);
    float ss0 = 0.f, ss1 = 0.f;
    for (int idx = lane; idx < c1; idx += 64) {
      float x0 = __expf(s_x0[w][idx] - m0), x1 = __expf(s_x1[w][idx] - m1);
      s_x0[w][idx] = x0; s_x1[w][idx] = x1;
      ss0 += x0; ss1 += x1;
    }
    for (int idx = CAP + lane; idx < tot; idx += 64) {
      int s = (idx < cnt) ? csr[beg + idx] : wid;
      float2 av = ((const float2*)a_s)[s];
      float e0 = av.x + ad0; e0 = e0 > 0.f ? e0 : NEG * e0;
      float e1 = av.y + ad1; e1 = e1 > 0.f ? e1 : NEG * e1;
      ss0 += __expf(e0 - m0); ss1 += __expf(e1 - m1);
    }
    inv0 = 1.f / wave_sum64(ss0); inv1 = 1.f / wave_sum64(ss1);
  }

  int gq = lane >> 4, q = lane & 15;
  bool hi = (q >= 8);                 // head of this lane's feature slice
  const int4* g4 = (const int4*)hg;   // 16 int4 per 128-feature row
  float acc[8] = {0.f, 0.f, 0.f, 0.f, 0.f, 0.f, 0.f, 0.f};
  for (int idx = gq; idx < c1; idx += 4) {
    int s = s_src[w][idx];
    float a = hi ? s_x1[w][idx] : s_x0[w][idx];
    fma8(acc, g4[(size_t)s * 16 + q], a);
  }
  for (int idx = CAP + gq; idx < tot; idx += 4) {   // essentially never
    int s = (idx < cnt) ? csr[beg + idx] : wid;
    float e = (hi ? a_s[s * 2 + 1] + ad1 : a_s[s * 2] + ad0);
    e = e > 0.f ? e : NEG * e;
    float a = __expf(e - (hi ? m1 : m0));
    fma8(acc, g4[(size_t)s * 16 + q], a);
  }
#pragma unroll
  for (int j = 0; j < 8; ++j) {
    acc[j] += __shfl_xor(acc[j], 16, 64);
    acc[j] += __shfl_xor(acc[j], 32, 64);
  }
  if (gq == 0) {   // lanes 0..15 write the full 256B row
    float invh = hi ? inv1 : inv0;
    u32 o[4];
#pragma unroll
    for (int p = 0; p < 4; ++p) {
      float v0 = fmaxf(acc[2 * p] * invh + bias[8 * q + 2 * p], 0.f);
      float v1 = fmaxf(acc[2 * p + 1] * invh + bias[8 * q + 2 * p + 1], 0.f);
      o[p] = pack2bf(v0, v1);
    }
    ((int4*)outb)[(size_t)wid * 16 + q] = *(int4*)o;
  }
}

// ---- GAT layer 2: 8 lanes/row int4, 8 edges/pass; head-mean + lsm --------
__global__ void k_gat2(const u16* __restrict__ hg, const float* __restrict__ a_s,
                       const float* __restrict__ a_d, const int* __restrict__ rowp,
                       const int* __restrict__ csr, const float* __restrict__ bias,
                       float* __restrict__ out) {
  __shared__ int   s_src[4][CAP];
  __shared__ float s_x0[4][CAP];
  __shared__ float s_x1[4][CAP];
  int wid = (blockIdx.x * blockDim.x + threadIdx.x) >> 6;
  int w = (threadIdx.x >> 6) & 3;
  int lane = threadIdx.x & 63;
  if (wid >= NN) return;
  int beg = rowp[wid], cnt = rowp[wid + 1] - beg;
  int tot = cnt + 1;
  int c1 = min(tot, CAP);
  float ad0 = a_d[wid * 2], ad1 = a_d[wid * 2 + 1];
  float m0, m1, inv0, inv1;

  if (tot <= 64) {
    bool act = lane < tot;
    int s = (lane < cnt) ? csr[beg + lane] : wid;
    float e0 = -1e30f, e1 = -1e30f;
    if (act) {
      float2 av = ((const float2*)a_s)[s];
      e0 = av.x + ad0; e0 = e0 > 0.f ? e0 : NEG * e0;
      e1 = av.y + ad1; e1 = e1 > 0.f ? e1 : NEG * e1;
    }
    m0 = wave_max64(e0); m1 = wave_max64(e1);
    float x0 = act ? __expf(e0 - m0) : 0.f;
    float x1 = act ? __expf(e1 - m1) : 0.f;
    inv0 = 1.f / wave_sum64(x0); inv1 = 1.f / wave_sum64(x1);
    if (act) { s_src[w][lane] = s; s_x0[w][lane] = x0; s_x1[w][lane] = x1; }
  } else {
    float mm0 = -1e30f, mm1 = -1e30f;
    for (int idx = lane; idx < tot; idx += 64) {
      int s = (idx < cnt) ? csr[beg + idx] : wid;
      float2 av = ((const float2*)a_s)[s];
      float e0 = av.x + ad0; e0 = e0 > 0.f ? e0 : NEG * e0;
      float e1 = av.y + ad1; e1 = e1 > 0.f ? e1 : NEG * e1;
      if (idx < CAP) { s_src[w][idx] = s; s_x0[w][idx] = e0; s_x1[w][idx] = e1; }
      mm0 = fmaxf(mm0, e0); mm1 = fmaxf(mm1, e1);
    }
    m0 = wave_max64(mm0); m1 = wave_max64(mm1);
    float ss0 = 0.f, ss1 = 0.f;
    for (int idx = lane; idx < c1; idx += 64) {
      float x0 = __expf(s_x0[w][idx] - m0), x1 = __expf(s_x1[w][idx] - m1);
      s_x0[w][idx] = x0; s_x1[w][idx] = x1;
      ss0 += x0; ss1 += x1;
    }
    for (int idx = CAP + lane; idx < tot; idx += 64) {
      int s = (idx < cnt) ? csr[beg + idx] : wid;
      float2 av = ((const float2*)a_s)[s];
      float e0 = av.x + ad0; e0 = e0 > 0.f ? e0 : NEG * e0;
      float e1 = av.y + ad1; e1 = e1 > 0.f ? e1 : NEG * e1;
      ss0 += __expf(e0 - m0); ss1 += __expf(e1 - m1);
    }
    inv0 = 1.f / wave_sum64(ss0); inv1 = 1.f / wave_sum64(ss1);
  }

  int gq = lane >> 3, q = lane & 7;
  bool hh = (q >= 4);                // head of this lane's feature slice
  const int4* g4 = (const int4*)hg;  // 8 int4 per 64-feature row
  float acc[8] = {0.f, 0.f, 0.f, 0.f, 0.f, 0.f, 0.f, 0.f};
  for (int idx = gq; idx < c1; idx += 8) {
    int s = s_src[w][idx];
    float a = hh ? s_x1[w][idx] : s_x0[w][idx];
    fma8(acc, g4[(size_t)s * 8 + q], a);
  }
  for (int idx = CAP + gq; idx < tot; idx += 8) {   // essentially never
    int s = (idx < cnt) ? csr[beg + idx] : wid;
    float e = (hh ? a_s[s * 2 + 1] + ad1 : a_s[s * 2] + ad0);
    e = e > 0.f ? e : NEG * e;
    float a = __expf(e - (hh ? m1 : m0));
    fma8(acc, g4[(size_t)s * 8 + q], a);
  }
#pragma unroll
  for (int j = 0; j < 8; ++j) {
    acc[j] += __shfl_xor(acc[j], 8, 64);
    acc[j] += __shfl_xor(acc[j], 16, 64);
    acc[j] += __shfl_xor(acc[j], 32, 64);
  }
  // normalize, head-mean (partner lane q^4 holds the other head's same chans)
  float invh = hh ? inv1 : inv0;
  float vv[8];
#pragma unroll
  for (int j = 0; j < 8; ++j) {
    float a = acc[j] * invh;
    vv[j] = 0.5f * (a + __shfl_xor(a, 4, 64)) + bias[8 * (q & 3) + j];
  }
  // log_softmax over 32 classes spread across q groups of 4 (dup on q>=4)
  float mx = vv[0];
#pragma unroll
  for (int j = 1; j < 8; ++j) mx = fmaxf(mx, vv[j]);
  mx = fmaxf(mx, __shfl_xor(mx, 1, 64));
  mx = fmaxf(mx, __shfl_xor(mx, 2, 64));
  float se = 0.f;
#pragma unroll
  for (int j = 0; j < 8; ++j) se += __expf(vv[j] - mx);
  se += __shfl_xor(se, 1, 64);
  se += __shfl_xor(se, 2, 64);
  float lse = mx + __logf(se);
  if (lane < 4) {   // lanes 0..3 write 8 floats each = full 32-class row
    float4 o0 = make_float4(vv[0] - lse, vv[1] - lse, vv[2] - lse, vv[3] - lse);
    float4 o1 = make_float4(vv[4] - lse, vv[5] - lse, vv[6] - lse, vv[7] - lse);
    float4* orow = (float4*)(out + (size_t)wid * 32);
    orow[q * 2] = o0;
    orow[q * 2 + 1] = o1;
  }
}

// --------------------------------------------------------------------------
extern "C" void kernel_launch(void* const* d_in, const int* in_sizes, int n_in,
                              void* d_out, int out_size, void* d_ws, size_t ws_size,
                              hipStream_t stream) {
  (void)in_sizes; (void)n_in; (void)out_size; (void)ws_size;
  const float* x   = (const float*)d_in[0];
  const void*  ei  = d_in[1];
  const float* W1  = (const float*)d_in[2];
  const float* b1  = (const float*)d_in[3];
  const float* W2  = (const float*)d_in[4];
  const float* b2  = (const float*)d_in[5];
  const float* Wg1 = (const float*)d_in[6];
  const float* as1 = (const float*)d_in[7];
  const float* ad1 = (const float*)d_in[8];
  const float* bg1 = (const float*)d_in[9];
  const float* Wg2 = (const float*)d_in[10];
  const float* as2 = (const float*)d_in[11];
  const float* ad2 = (const float*)d_in[12];
  const float* bg2 = (const float*)d_in[13];
  float* out = (float*)d_out;

  char* w = (char*)d_ws;
  auto alloc = [&](size_t bytes) { char* p = w; w += (bytes + 255) & ~(size_t)255; return p; };
  u16* Hb     = (u16*)alloc((size_t)NN * 128 * 2);   // GEMM outputs (bf16)
  u16* Xb     = (u16*)alloc((size_t)NN * 128 * 2);   // aggregation outputs (bf16)
  float* dinv = (float*)alloc((size_t)NN * 4);
  float* asb  = (float*)alloc((size_t)NN * 2 * 4);
  float* adb  = (float*)alloc((size_t)NN * 2 * 4);
  int* rowp   = (int*)alloc((size_t)(NN + 1) * 4);
  int* csr    = (int*)alloc((size_t)EE * 4);
  u32* buf    = (u32*)alloc((size_t)NBC * CAPB * 4);
  int* gcnt   = (int*)alloc((size_t)NBC * 4);
  int* csrbase= (int*)alloc((size_t)NBC * 4);
  int* flag   = (int*)alloc(16);

  const int TB = 256;
  int gW = (NN + 3) / 4;            // wave per node
  int gG = (NN + 63) / 64;          // 64-row GEMM blocks

  // CSR build (two-pass radix partition)
  k_probe<<<1, 256, 0, stream>>>(ei, flag, gcnt);
  k_part<<<256, TB, 0, stream>>>(ei, flag, gcnt, buf);
  k_scanb<<<1, 128, 0, stream>>>(gcnt, csrbase, rowp);
  k_csr2<<<NBC, TB, 0, stream>>>(buf, gcnt, csrbase, rowp, dinv, csr);

  // GCN 1
  k_mm<128, 64, true, false, 0><<<gG, TB, 0, stream>>>(x, W1, nullptr, nullptr, Hb, nullptr, nullptr);
  k_gcn<<<gW, TB, 0, stream>>>(Hb, dinv, rowp, csr, b1, Xb);
  // GCN 2
  k_mm<64, 64, false, false, 0><<<gG, TB, 0, stream>>>(Xb, W2, nullptr, nullptr, Hb, nullptr, nullptr);
  k_gcn<<<gW, TB, 0, stream>>>(Hb, dinv, rowp, csr, b2, Xb);
  // GAT 1 (concat, relu) + fused att coefficients
  k_mm<64, 128, false, true, 4><<<gG, TB, 0, stream>>>(Xb, Wg1, as1, ad1, Hb, asb, adb);
  k_gat1<<<gW, TB, 0, stream>>>(Hb, asb, adb, rowp, csr, bg1, Xb);
  // GAT 2 (head mean) + log_softmax, fused att coefficients
  k_mm<128, 64, false, true, 2><<<gG, TB, 0, stream>>>(Xb, Wg2, as2, ad2, Hb, asb, adb);
  k_gat2<<<gW, TB, 0, stream>>>(Hb, asb, adb, rowp, csr, bg2, out);
}

// Round 10
// 225.022 us; speedup vs baseline: 1.0034x; 1.0034x over previous
//
#include <hip/hip_runtime.h>

#define NN 50000
#define EE 800000
#define NEG 0.2f
#define CAP 128    // per-wave LDS edge stash (deg ~Poisson(16), max ~45; fallback kept)
#define NBC 98     // coarse buckets of 512 nodes for CSR build
#define BSH2 9
#define CAPB 16384 // buf capacity per bucket (mean 8163 -> huge margin)
#define PCH 3125   // edges per k_part block (256 * 3125 == EE exactly)

typedef long long i64;
typedef unsigned int u32;
typedef unsigned short u16;
typedef __attribute__((ext_vector_type(8))) short bf16x8;
typedef __attribute__((ext_vector_type(4))) float f32x4;

static __device__ __forceinline__ float wave_max64(float v) {
#pragma unroll
  for (int m = 32; m >= 1; m >>= 1) v = fmaxf(v, __shfl_xor(v, m, 64));
  return v;
}
static __device__ __forceinline__ float wave_sum64(float v) {
#pragma unroll
  for (int m = 32; m >= 1; m >>= 1) v += __shfl_xor(v, m, 64);
  return v;
}

// bf16 helpers
static __device__ __forceinline__ u16 f2bf(float f) {
  u32 u = __float_as_uint(f);
  u += 0x7FFFu + ((u >> 16) & 1u);
  return (u16)(u >> 16);
}
static __device__ __forceinline__ float bflo(u32 v) { return __uint_as_float(v << 16); }
static __device__ __forceinline__ float bfhi(u32 v) { return __uint_as_float(v & 0xffff0000u); }
static __device__ __forceinline__ u32 pack2bf(float a, float b) {
  return (u32)f2bf(a) | ((u32)f2bf(b) << 16);
}
static __device__ __forceinline__ void fma8(float* acc, int4 v, float a) {
  acc[0] += bflo(v.x) * a; acc[1] += bfhi(v.x) * a;
  acc[2] += bflo(v.y) * a; acc[3] += bfhi(v.y) * a;
  acc[4] += bflo(v.z) * a; acc[5] += bfhi(v.z) * a;
  acc[6] += bflo(v.w) * a; acc[7] += bfhi(v.w) * a;
}

// ---- dtype probe + zero bucket counters ----------------------------------
__global__ void k_probe(const void* ei, int* flag, int* gcnt) {
  __shared__ int sbad[4];
  int t = threadIdx.x;
  if (t < NBC) gcnt[t] = 0;
  const i64* p = (const i64*)ei;
  i64 v = p[t];
  int bad = (v < 0 || v >= NN) ? 1 : 0;
  unsigned long long b = __ballot(bad);
  if ((t & 63) == 0) sbad[t >> 6] = (b != 0ULL);
  __syncthreads();
  if (t == 0) *flag = !(sbad[0] | sbad[1] | sbad[2] | sbad[3]);
}

static __device__ __forceinline__ int edge_at(const void* ei, int is64, int idx) {
  return is64 ? (int)((const i64*)ei)[idx] : ((const int*)ei)[idx];
}

// ---- pass 1: per-block LDS counting sort into 98 coarse buckets ----------
__global__ void k_part(const void* ei, const int* flag, int* gcnt, u32* buf) {
  __shared__ u32 lbuf[PCH];
  __shared__ int hist[128], offb[128], curb[128], gbase[128], sc[128];
  int t = threadIdx.x;
  int is64 = *flag;
  if (t < 128) { hist[t] = 0; curb[t] = 0; }
  __syncthreads();
  int lo = blockIdx.x * PCH;

  for (int e = lo + t; e < lo + PCH; e += 256)
    atomicAdd(&hist[edge_at(ei, is64, EE + e) >> BSH2], 1);
  __syncthreads();

  if (t < 128) sc[t] = hist[t];
  __syncthreads();
  for (int o = 1; o < 128; o <<= 1) {
    int v = (t >= o && t < 128) ? sc[t - o] : 0;
    __syncthreads();
    if (t < 128) sc[t] += v;
    __syncthreads();
  }
  if (t < 128) offb[t] = sc[t] - hist[t];
  __syncthreads();

  for (int e = lo + t; e < lo + PCH; e += 256) {
    int s = edge_at(ei, is64, e);
    int d = edge_at(ei, is64, EE + e);
    int b = d >> BSH2;
    u32 v = (u32)s | ((u32)(d & 511) << 16) | ((u32)b << 25);
    int p = atomicAdd(&curb[b], 1);
    lbuf[offb[b] + p] = v;
  }
  __syncthreads();

  if (t < 128) {
    int c = hist[t];
    gbase[t] = c ? atomicAdd(&gcnt[t], c) : 0;
  }
  __syncthreads();

  for (int i = t; i < PCH; i += 256) {
    u32 v = lbuf[i];
    int b = v >> 25;
    int pos = gbase[b] + (i - offb[b]);
    if (pos < CAPB) buf[(size_t)b * CAPB + pos] = v;
  }
}

// ---- pass 2: exclusive scan of bucket counts -----------------------------
__global__ void k_scanb(const int* gcnt, int* csrbase, int* rowp) {
  __shared__ int sc[128];
  int t = threadIdx.x;
  int c = (t < NBC) ? min(gcnt[t], CAPB) : 0;
  sc[t] = c;
  __syncthreads();
  for (int o = 1; o < 128; o <<= 1) {
    int v = (t >= o) ? sc[t - o] : 0;
    __syncthreads();
    sc[t] += v;
    __syncthreads();
  }
  if (t < NBC) csrbase[t] = sc[t] - c;
  if (t == 127) rowp[NN] = sc[127];
}

// ---- pass 3: per-bucket local sort -> rowp, dinv, csr --------------------
__global__ void k_csr2(const u32* __restrict__ buf, const int* __restrict__ gcnt,
                       const int* __restrict__ csrbase, int* __restrict__ rowp,
                       float* __restrict__ dinv, int* __restrict__ csr) {
  __shared__ int hist[512], offs[512], cur[512], sc[256];
  int b = blockIdx.x;
  int t = threadIdx.x;
  int cnt = min(gcnt[b], CAPB);
  const u32* mb = buf + (size_t)b * CAPB;
  int cbase = csrbase[b];
  int nbase = b << BSH2;
  int nn = min(512, NN - nbase);
  hist[t] = 0; hist[t + 256] = 0; cur[t] = 0; cur[t + 256] = 0;
  __syncthreads();
  for (int i = t; i < cnt; i += 256) atomicAdd(&hist[(mb[i] >> 16) & 511], 1);
  __syncthreads();
  int a0 = hist[2 * t], a1 = hist[2 * t + 1];
  sc[t] = a0 + a1;
  __syncthreads();
  for (int o = 1; o < 256; o <<= 1) {
    int v = (t >= o) ? sc[t - o] : 0;
    __syncthreads();
    sc[t] += v;
    __syncthreads();
  }
  int excl = sc[t] - (a0 + a1);
  offs[2 * t] = excl; offs[2 * t + 1] = excl + a0;
  __syncthreads();
  for (int i = t; i < nn; i += 256) {
    rowp[nbase + i] = cbase + offs[i];
    dinv[nbase + i] = rsqrtf((float)(hist[i] + 1));
  }
  for (int i = t; i < cnt; i += 256) {
    u32 v = mb[i];
    int dl = (v >> 16) & 511;
    int p = atomicAdd(&cur[dl], 1);
    csr[cbase + offs[dl] + p] = (int)(v & 0xFFFF);
  }
}

// ---- MFMA GEMM (as round 8) ----------------------------------------------
template <int K, int N, bool SRCF32, bool ATT, int NTH>
__global__ void k_mm(const void* __restrict__ Xsrc, const float* __restrict__ W,
                     const float* __restrict__ aw_s, const float* __restrict__ aw_d,
                     u16* __restrict__ Y, float* __restrict__ a_sv,
                     float* __restrict__ a_dv) {
  constexpr int BM = 64;
  constexpr int NT = N / 16;
  constexpr int KS = K / 32;
  __shared__ u16 Ab[BM * K];
  __shared__ u16 Wt[N * K];
  int t = threadIdx.x;
  int blockRow = blockIdx.x * BM;

  if (SRCF32) {
    const float4* Xq = (const float4*)Xsrc + (size_t)blockRow * (K / 4);
    for (int i = t; i < BM * K / 4; i += 256) {
      int r = (i * 4) / K;
      float4 v = (blockRow + r < NN) ? Xq[i] : make_float4(0.f, 0.f, 0.f, 0.f);
      ushort4 p = make_ushort4(f2bf(v.x), f2bf(v.y), f2bf(v.z), f2bf(v.w));
      int b = i * 8;
      *(ushort4*)((char*)Ab + (b ^ ((r & 7) << 4))) = p;
    }
  } else {
    const int4* Xq = (const int4*)Xsrc + (size_t)blockRow * (K / 8);
    for (int i = t; i < BM * K / 8; i += 256) {
      int r = (i * 8) / K;
      int4 v = (blockRow + r < NN) ? Xq[i] : make_int4(0, 0, 0, 0);
      int b = i * 16;
      *(int4*)((char*)Ab + (b ^ ((r & 7) << 4))) = v;
    }
  }
  for (int i = t; i < K * N; i += 256) {
    int k = i / N, n = i % N;
    int b = (n * K + k) * 2;
    *(u16*)((char*)Wt + (b ^ ((n & 7) << 4))) = f2bf(W[i]);
  }
  __syncthreads();

  int w = t >> 6, l = t & 63;
  int lr = l & 15, lg = l >> 4;
  int sw = (lr & 7) << 4;
  f32x4 acc[NT];
#pragma unroll
  for (int nt = 0; nt < NT; ++nt) acc[nt] = (f32x4)0.f;

#pragma unroll
  for (int ks = 0; ks < KS; ++ks) {
    int ar = 16 * w + lr;
    int ab = (ar * K + ks * 32 + lg * 8) * 2;
    bf16x8 af = *(bf16x8*)((char*)Ab + (ab ^ sw));
#pragma unroll
    for (int nt = 0; nt < NT; ++nt) {
      int bb = ((nt * 16 + lr) * K + ks * 32 + lg * 8) * 2;
      bf16x8 bfr = *(bf16x8*)((char*)Wt + (bb ^ sw));
      acc[nt] = __builtin_amdgcn_mfma_f32_16x16x32_bf16(af, bfr, acc[nt], 0, 0, 0);
    }
  }

#pragma unroll
  for (int j = 0; j < 4; ++j) {
    int row = blockRow + 16 * w + lg * 4 + j;
    if (row < NN) {
      u16* yr = Y + (size_t)row * N + lr;
#pragma unroll
      for (int nt = 0; nt < NT; ++nt) yr[nt * 16] = f2bf(acc[nt][j]);
    }
  }

  if (ATT) {
    float aws[NT], awd[NT];
#pragma unroll
    for (int nt = 0; nt < NT; ++nt) {
      aws[nt] = aw_s[nt * 16 + lr];
      awd[nt] = aw_d[nt * 16 + lr];
    }
#pragma unroll
    for (int j = 0; j < 4; ++j) {
      int row = blockRow + 16 * w + lg * 4 + j;
#pragma unroll
      for (int h = 0; h < 2; ++h) {
        float s = 0.f, d = 0.f;
#pragma unroll
        for (int q = 0; q < NTH; ++q) {
          int nt = h * NTH + q;
          s += acc[nt][j] * aws[nt];
          d += acc[nt][j] * awd[nt];
        }
#pragma unroll
        for (int mm = 8; mm >= 1; mm >>= 1) {
          s += __shfl_xor(s, mm, 64);
          d += __shfl_xor(d, mm, 64);
        }
        if (lr == 0 && row < NN) {
          a_sv[row * 2 + h] = s;
          a_dv[row * 2 + h] = d;
        }
      }
    }
  }
}

// ---- GCN aggregation: 8 lanes/row int4, padded + pipelined ---------------
__global__ void k_gcn(const u16* __restrict__ g, const float* __restrict__ dinv,
                      const int* __restrict__ rowp, const int* __restrict__ csr,
                      const float* __restrict__ bias, u16* __restrict__ outb) {
  __shared__ int   s_src[4][CAP];
  __shared__ float s_wt[4][CAP];
  int wid = (blockIdx.x * blockDim.x + threadIdx.x) >> 6;
  int w = (threadIdx.x >> 6) & 3;
  int lane = threadIdx.x & 63;
  if (wid >= NN) return;
  float di = dinv[wid];
  int beg = rowp[wid], cnt = rowp[wid + 1] - beg;
  int tot = cnt + 1;                 // self loop at idx == cnt
  int c1 = min(tot, CAP);
  int c1p = (c1 + 7) & ~7;           // pad to group multiple (<= CAP)

  for (int idx = lane; idx < c1p; idx += 64) {
    int s; float wt;
    if (idx < cnt)      { s = csr[beg + idx]; wt = dinv[s]; }
    else if (idx < tot) { s = wid; wt = di; }
    else                { s = wid; wt = 0.f; }
    s_src[w][idx] = s; s_wt[w][idx] = wt;
  }

  int gq = lane >> 3, q = lane & 7;
  const int4* g4 = (const int4*)g;   // 8 int4 per 64-feature row
  float acc[8] = {0.f, 0.f, 0.f, 0.f, 0.f, 0.f, 0.f, 0.f};
  int np = c1p >> 3;                 // >= 1 (tot >= 1)
  int s0 = s_src[w][gq];
  float a0 = s_wt[w][gq];
  int4 v0 = g4[(size_t)s0 * 8 + q];
  for (int p = 1; p < np; ++p) {
    int i1 = gq + (p << 3);
    int s1 = s_src[w][i1];
    float a1 = s_wt[w][i1];
    int4 v1 = g4[(size_t)s1 * 8 + q];
    fma8(acc, v0, a0);
    v0 = v1; a0 = a1;
  }
  fma8(acc, v0, a0);
  for (int idx = CAP + gq; idx < tot; idx += 8) {   // essentially never
    int s = (idx < cnt) ? csr[beg + idx] : wid;
    float a = (idx < cnt) ? dinv[s] : di;
    fma8(acc, g4[(size_t)s * 8 + q], a);
  }
#pragma unroll
  for (int j = 0; j < 8; ++j) {
    acc[j] += __shfl_xor(acc[j], 8, 64);
    acc[j] += __shfl_xor(acc[j], 16, 64);
    acc[j] += __shfl_xor(acc[j], 32, 64);
  }
  if (gq == 0) {
    u32 o[4];
#pragma unroll
    for (int p = 0; p < 4; ++p) {
      float v0f = fmaxf(acc[2 * p] * di + bias[8 * q + 2 * p], 0.f);
      float v1f = fmaxf(acc[2 * p + 1] * di + bias[8 * q + 2 * p + 1], 0.f);
      o[p] = pack2bf(v0f, v1f);
    }
    ((int4*)outb)[(size_t)wid * 8 + q] = *(int4*)o;
  }
}

// ---- GAT layer 1: 16 lanes/row int4, padded + pipelined ------------------
__global__ void k_gat1(const u16* __restrict__ hg, const float* __restrict__ a_s,
                       const float* __restrict__ a_d, const int* __restrict__ rowp,
                       const int* __restrict__ csr, const float* __restrict__ bias,
                       u16* __restrict__ outb) {
  __shared__ int   s_src[4][CAP];
  __shared__ float s_x[4][CAP][2];   // interleaved per-head alpha
  int wid = (blockIdx.x * blockDim.x + threadIdx.x) >> 6;
  int w = (threadIdx.x >> 6) & 3;
  int lane = threadIdx.x & 63;
  if (wid >= NN) return;
  int beg = rowp[wid], cnt = rowp[wid + 1] - beg;
  int tot = cnt + 1;
  int c1 = min(tot, CAP);
  int c1p = (c1 + 3) & ~3;
  float ad0 = a_d[wid * 2], ad1 = a_d[wid * 2 + 1];
  float m0, m1, inv0, inv1;

  if (tot <= 64) {  // fast path: one edge per lane, straight-line softmax
    bool act = lane < tot;
    int s = (lane < cnt) ? csr[beg + lane] : wid;
    float e0 = -1e30f, e1 = -1e30f;
    if (act) {
      float2 av = ((const float2*)a_s)[s];
      e0 = av.x + ad0; e0 = e0 > 0.f ? e0 : NEG * e0;
      e1 = av.y + ad1; e1 = e1 > 0.f ? e1 : NEG * e1;
    }
    m0 = wave_max64(e0); m1 = wave_max64(e1);
    float x0 = act ? __expf(e0 - m0) : 0.f;
    float x1 = act ? __expf(e1 - m1) : 0.f;
    inv0 = 1.f / wave_sum64(x0); inv1 = 1.f / wave_sum64(x1);
    if (lane < c1p) {                // real entries + zero pads
      s_src[w][lane] = s;
      s_x[w][lane][0] = x0;
      s_x[w][lane][1] = x1;
    }
  } else {  // generic fallback
    float mm0 = -1e30f, mm1 = -1e30f;
    for (int idx = lane; idx < tot; idx += 64) {
      int s = (idx < cnt) ? csr[beg + idx] : wid;
      float2 av = ((const float2*)a_s)[s];
      float e0 = av.x + ad0; e0 = e0 > 0.f ? e0 : NEG * e0;
      float e1 = av.y + ad1; e1 = e1 > 0.f ? e1 : NEG * e1;
      if (idx < CAP) { s_src[w][idx] = s; s_x[w][idx][0] = e0; s_x[w][idx][1] = e1; }
      mm0 = fmaxf(mm0, e0); mm1 = fmaxf(mm1, e1);
    }
    m0 = wave_max64(mm0); m1 = wave_max64(mm1);
    float ss0 = 0.f, ss1 = 0.f;
    for (int idx = lane; idx < c1; idx += 64) {
      float x0 = __expf(s_x[w][idx][0] - m0), x1 = __expf(s_x[w][idx][1] - m1);
      s_x[w][idx][0] = x0; s_x[w][idx][1] = x1;
      ss0 += x0; ss1 += x1;
    }
    for (int idx = CAP + lane; idx < tot; idx += 64) {
      int s = (idx < cnt) ? csr[beg + idx] : wid;
      float2 av = ((const float2*)a_s)[s];
      float e0 = av.x + ad0; e0 = e0 > 0.f ? e0 : NEG * e0;
      float e1 = av.y + ad1; e1 = e1 > 0.f ? e1 : NEG * e1;
      ss0 += __expf(e0 - m0); ss1 += __expf(e1 - m1);
    }
    inv0 = 1.f / wave_sum64(ss0); inv1 = 1.f / wave_sum64(ss1);
    int ip = c1 + lane;
    if (ip < c1p) { s_src[w][ip] = wid; s_x[w][ip][0] = 0.f; s_x[w][ip][1] = 0.f; }
  }

  int gq = lane >> 4, q = lane & 15;
  int hh = q >> 3;                    // head of this lane's feature slice
  const int4* g4 = (const int4*)hg;   // 16 int4 per 128-feature row
  float acc[8] = {0.f, 0.f, 0.f, 0.f, 0.f, 0.f, 0.f, 0.f};
  int np = c1p >> 2;
  int s0 = s_src[w][gq];
  float a0 = s_x[w][gq][hh];
  int4 v0 = g4[(size_t)s0 * 16 + q];
  for (int p = 1; p < np; ++p) {
    int i1 = gq + (p << 2);
    int s1 = s_src[w][i1];
    float a1 = s_x[w][i1][hh];
    int4 v1 = g4[(size_t)s1 * 16 + q];
    fma8(acc, v0, a0);
    v0 = v1; a0 = a1;
  }
  fma8(acc, v0, a0);
  for (int idx = CAP + gq; idx < tot; idx += 4) {   // essentially never
    int s = (idx < cnt) ? csr[beg + idx] : wid;
    float e = (hh ? a_s[s * 2 + 1] + ad1 : a_s[s * 2] + ad0);
    e = e > 0.f ? e : NEG * e;
    float a = __expf(e - (hh ? m1 : m0));
    fma8(acc, g4[(size_t)s * 16 + q], a);
  }
#pragma unroll
  for (int j = 0; j < 8; ++j) {
    acc[j] += __shfl_xor(acc[j], 16, 64);
    acc[j] += __shfl_xor(acc[j], 32, 64);
  }
  if (gq == 0) {   // lanes 0..15 write the full 256B row
    float invh = hh ? inv1 : inv0;
    u32 o[4];
#pragma unroll
    for (int p = 0; p < 4; ++p) {
      float v0f = fmaxf(acc[2 * p] * invh + bias[8 * q + 2 * p], 0.f);
      float v1f = fmaxf(acc[2 * p + 1] * invh + bias[8 * q + 2 * p + 1], 0.f);
      o[p] = pack2bf(v0f, v1f);
    }
    ((int4*)outb)[(size_t)wid * 16 + q] = *(int4*)o;
  }
}

// ---- GAT layer 2: 8 lanes/row int4, padded + pipelined; mean + lsm -------
__global__ void k_gat2(const u16* __restrict__ hg, const float* __restrict__ a_s,
                       const float* __restrict__ a_d, const int* __restrict__ rowp,
                       const int* __restrict__ csr, const float* __restrict__ bias,
                       float* __restrict__ out) {
  __shared__ int   s_src[4][CAP];
  __shared__ float s_x[4][CAP][2];
  int wid = (blockIdx.x * blockDim.x + threadIdx.x) >> 6;
  int w = (threadIdx.x >> 6) & 3;
  int lane = threadIdx.x & 63;
  if (wid >= NN) return;
  int beg = rowp[wid], cnt = rowp[wid + 1] - beg;
  int tot = cnt + 1;
  int c1 = min(tot, CAP);
  int c1p = (c1 + 7) & ~7;
  float ad0 = a_d[wid * 2], ad1 = a_d[wid * 2 + 1];
  float m0, m1, inv0, inv1;

  if (tot <= 64) {
    bool act = lane < tot;
    int s = (lane < cnt) ? csr[beg + lane] : wid;
    float e0 = -1e30f, e1 = -1e30f;
    if (act) {
      float2 av = ((const float2*)a_s)[s];
      e0 = av.x + ad0; e0 = e0 > 0.f ? e0 : NEG * e0;
      e1 = av.y + ad1; e1 = e1 > 0.f ? e1 : NEG * e1;
    }
    m0 = wave_max64(e0); m1 = wave_max64(e1);
    float x0 = act ? __expf(e0 - m0) : 0.f;
    float x1 = act ? __expf(e1 - m1) : 0.f;
    inv0 = 1.f / wave_sum64(x0); inv1 = 1.f / wave_sum64(x1);
    if (lane < c1p) {
      s_src[w][lane] = s;
      s_x[w][lane][0] = x0;
      s_x[w][lane][1] = x1;
    }
  } else {
    float mm0 = -1e30f, mm1 = -1e30f;
    for (int idx = lane; idx < tot; idx += 64) {
      int s = (idx < cnt) ? csr[beg + idx] : wid;
      float2 av = ((const float2*)a_s)[s];
      float e0 = av.x + ad0; e0 = e0 > 0.f ? e0 : NEG * e0;
      float e1 = av.y + ad1; e1 = e1 > 0.f ? e1 : NEG * e1;
      if (idx < CAP) { s_src[w][idx] = s; s_x[w][idx][0] = e0; s_x[w][idx][1] = e1; }
      mm0 = fmaxf(mm0, e0); mm1 = fmaxf(mm1, e1);
    }
    m0 = wave_max64(mm0); m1 = wave_max64(mm1);
    float ss0 = 0.f, ss1 = 0.f;
    for (int idx = lane; idx < c1; idx += 64) {
      float x0 = __expf(s_x[w][idx][0] - m0), x1 = __expf(s_x[w][idx][1] - m1);
      s_x[w][idx][0] = x0; s_x[w][idx][1] = x1;
      ss0 += x0; ss1 += x1;
    }
    for (int idx = CAP + lane; idx < tot; idx += 64) {
      int s = (idx < cnt) ? csr[beg + idx] : wid;
      float2 av = ((const float2*)a_s)[s];
      float e0 = av.x + ad0; e0 = e0 > 0.f ? e0 : NEG * e0;
      float e1 = av.y + ad1; e1 = e1 > 0.f ? e1 : NEG * e1;
      ss0 += __expf(e0 - m0); ss1 += __expf(e1 - m1);
    }
    inv0 = 1.f / wave_sum64(ss0); inv1 = 1.f / wave_sum64(ss1);
    int ip = c1 + lane;
    if (ip < c1p) { s_src[w][ip] = wid; s_x[w][ip][0] = 0.f; s_x[w][ip][1] = 0.f; }
  }

  int gq = lane >> 3, q = lane & 7;
  int hh = q >> 2;                   // head of this lane's feature slice
  const int4* g4 = (const int4*)hg;  // 8 int4 per 64-feature row
  float acc[8] = {0.f, 0.f, 0.f, 0.f, 0.f, 0.f, 0.f, 0.f};
  int np = c1p >> 3;
  int s0 = s_src[w][gq];
  float a0 = s_x[w][gq][hh];
  int4 v0 = g4[(size_t)s0 * 8 + q];
  for (int p = 1; p < np; ++p) {
    int i1 = gq + (p << 3);
    int s1 = s_src[w][i1];
    float a1 = s_x[w][i1][hh];
    int4 v1 = g4[(size_t)s1 * 8 + q];
    fma8(acc, v0, a0);
    v0 = v1; a0 = a1;
  }
  fma8(acc, v0, a0);
  for (int idx = CAP + gq; idx < tot; idx += 8) {   // essentially never
    int s = (idx < cnt) ? csr[beg + idx] : wid;
    float e = (hh ? a_s[s * 2 + 1] + ad1 : a_s[s * 2] + ad0);
    e = e > 0.f ? e : NEG * e;
    float a = __expf(e - (hh ? m1 : m0));
    fma8(acc, g4[(size_t)s * 8 + q], a);
  }
#pragma unroll
  for (int j = 0; j < 8; ++j) {
    acc[j] += __shfl_xor(acc[j], 8, 64);
    acc[j] += __shfl_xor(acc[j], 16, 64);
    acc[j] += __shfl_xor(acc[j], 32, 64);
  }
  // normalize, head-mean (partner lane q^4 holds the other head's same chans)
  float invh = hh ? inv1 : inv0;
  float vv[8];
#pragma unroll
  for (int j = 0; j < 8; ++j) {
    float a = acc[j] * invh;
    vv[j] = 0.5f * (a + __shfl_xor(a, 4, 64)) + bias[8 * (q & 3) + j];
  }
  float mx = vv[0];
#pragma unroll
  for (int j = 1; j < 8; ++j) mx = fmaxf(mx, vv[j]);
  mx = fmaxf(mx, __shfl_xor(mx, 1, 64));
  mx = fmaxf(mx, __shfl_xor(mx, 2, 64));
  float se = 0.f;
#pragma unroll
  for (int j = 0; j < 8; ++j) se += __expf(vv[j] - mx);
  se += __shfl_xor(se, 1, 64);
  se += __shfl_xor(se, 2, 64);
  float lse = mx + __logf(se);
  if (lane < 4) {
    float4 o0 = make_float4(vv[0] - lse, vv[1] - lse, vv[2] - lse, vv[3] - lse);
    float4 o1 = make_float4(vv[4] - lse, vv[5] - lse, vv[6] - lse, vv[7] - lse);
    float4* orow = (float4*)(out + (size_t)wid * 32);
    orow[q * 2] = o0;
    orow[q * 2 + 1] = o1;
  }
}

// --------------------------------------------------------------------------
extern "C" void kernel_launch(void* const* d_in, const int* in_sizes, int n_in,
                              void* d_out, int out_size, void* d_ws, size_t ws_size,
                              hipStream_t stream) {
  (void)in_sizes; (void)n_in; (void)out_size; (void)ws_size;
  const float* x   = (const float*)d_in[0];
  const void*  ei  = d_in[1];
  const float* W1  = (const float*)d_in[2];
  const float* b1  = (const float*)d_in[3];
  const float* W2  = (const float*)d_in[4];
  const float* b2  = (const float*)d_in[5];
  const float* Wg1 = (const float*)d_in[6];
  const float* as1 = (const float*)d_in[7];
  const float* ad1 = (const float*)d_in[8];
  const float* bg1 = (const float*)d_in[9];
  const float* Wg2 = (const float*)d_in[10];
  const float* as2 = (const float*)d_in[11];
  const float* ad2 = (const float*)d_in[12];
  const float* bg2 = (const float*)d_in[13];
  float* out = (float*)d_out;

  char* w = (char*)d_ws;
  auto alloc = [&](size_t bytes) { char* p = w; w += (bytes + 255) & ~(size_t)255; return p; };
  u16* Hb     = (u16*)alloc((size_t)NN * 128 * 2);   // GEMM outputs (bf16)
  u16* Xb     = (u16*)alloc((size_t)NN * 128 * 2);   // aggregation outputs (bf16)
  float* dinv = (float*)alloc((size_t)NN * 4);
  float* asb  = (float*)alloc((size_t)NN * 2 * 4);
  float* adb  = (float*)alloc((size_t)NN * 2 * 4);
  int* rowp   = (int*)alloc((size_t)(NN + 1) * 4);
  int* csr    = (int*)alloc((size_t)EE * 4);
  u32* buf    = (u32*)alloc((size_t)NBC * CAPB * 4);
  int* gcnt   = (int*)alloc((size_t)NBC * 4);
  int* csrbase= (int*)alloc((size_t)NBC * 4);
  int* flag   = (int*)alloc(16);

  const int TB = 256;
  int gW = (NN + 3) / 4;            // wave per node
  int gG = (NN + 63) / 64;          // 64-row GEMM blocks

  // CSR build (two-pass radix partition)
  k_probe<<<1, 256, 0, stream>>>(ei, flag, gcnt);
  k_part<<<256, TB, 0, stream>>>(ei, flag, gcnt, buf);
  k_scanb<<<1, 128, 0, stream>>>(gcnt, csrbase, rowp);
  k_csr2<<<NBC, TB, 0, stream>>>(buf, gcnt, csrbase, rowp, dinv, csr);

  // GCN 1
  k_mm<128, 64, true, false, 0><<<gG, TB, 0, stream>>>(x, W1, nullptr, nullptr, Hb, nullptr, nullptr);
  k_gcn<<<gW, TB, 0, stream>>>(Hb, dinv, rowp, csr, b1, Xb);
  // GCN 2
  k_mm<64, 64, false, false, 0><<<gG, TB, 0, stream>>>(Xb, W2, nullptr, nullptr, Hb, nullptr, nullptr);
  k_gcn<<<gW, TB, 0, stream>>>(Hb, dinv, rowp, csr, b2, Xb);
  // GAT 1 (concat, relu) + fused att coefficients
  k_mm<64, 128, false, true, 4><<<gG, TB, 0, stream>>>(Xb, Wg1, as1, ad1, Hb, asb, adb);
  k_gat1<<<gW, TB, 0, stream>>>(Hb, asb, adb, rowp, csr, bg1, Xb);
  // GAT 2 (head mean) + log_softmax, fused att coefficients
  k_mm<128, 64, false, true, 2><<<gG, TB, 0, stream>>>(Xb, Wg2, as2, ad2, Hb, asb, adb);
  k_gat2<<<gW, TB, 0, stream>>>(Hb, asb, adb, rowp, csr, bg2, out);
}

// Round 11
// 190.391 us; speedup vs baseline: 1.1859x; 1.1819x over previous
//
#include <hip/hip_runtime.h>

#define NN 50000
#define EE 800000
#define NEG 0.2f
#define CAP 64     // per-node LDS edge stash (deg ~Poisson(16), max ~45; fallback kept)
#define NBC 98     // coarse buckets of 512 nodes for CSR build
#define BSH2 9
#define CAPB 16384 // buf capacity per bucket (mean 8163 -> huge margin)
#define PCH 3125   // edges per k_part block (256 * 3125 == EE exactly)

typedef long long i64;
typedef unsigned int u32;
typedef unsigned short u16;
typedef __attribute__((ext_vector_type(8))) short bf16x8;
typedef __attribute__((ext_vector_type(4))) float f32x4;

// bf16 helpers
static __device__ __forceinline__ u16 f2bf(float f) {
  u32 u = __float_as_uint(f);
  u += 0x7FFFu + ((u >> 16) & 1u);
  return (u16)(u >> 16);
}
static __device__ __forceinline__ float bflo(u32 v) { return __uint_as_float(v << 16); }
static __device__ __forceinline__ float bfhi(u32 v) { return __uint_as_float(v & 0xffff0000u); }
static __device__ __forceinline__ u32 pack2bf(float a, float b) {
  return (u32)f2bf(a) | ((u32)f2bf(b) << 16);
}
static __device__ __forceinline__ void fma8(float* acc, int4 v, float a) {
  acc[0] += bflo(v.x) * a; acc[1] += bfhi(v.x) * a;
  acc[2] += bflo(v.y) * a; acc[3] += bfhi(v.y) * a;
  acc[4] += bflo(v.z) * a; acc[5] += bfhi(v.z) * a;
  acc[6] += bflo(v.w) * a; acc[7] += bfhi(v.w) * a;
}

// ---- dtype probe + zero bucket counters ----------------------------------
__global__ void k_probe(const void* ei, int* flag, int* gcnt) {
  __shared__ int sbad[4];
  int t = threadIdx.x;
  if (t < NBC) gcnt[t] = 0;
  const i64* p = (const i64*)ei;
  i64 v = p[t];
  int bad = (v < 0 || v >= NN) ? 1 : 0;
  unsigned long long b = __ballot(bad);
  if ((t & 63) == 0) sbad[t >> 6] = (b != 0ULL);
  __syncthreads();
  if (t == 0) *flag = !(sbad[0] | sbad[1] | sbad[2] | sbad[3]);
}

static __device__ __forceinline__ int edge_at(const void* ei, int is64, int idx) {
  return is64 ? (int)((const i64*)ei)[idx] : ((const int*)ei)[idx];
}

// ---- pass 1: per-block LDS counting sort into 98 coarse buckets ----------
__global__ void k_part(const void* ei, const int* flag, int* gcnt, u32* buf) {
  __shared__ u32 lbuf[PCH];
  __shared__ int hist[128], offb[128], curb[128], gbase[128], sc[128];
  int t = threadIdx.x;
  int is64 = *flag;
  if (t < 128) { hist[t] = 0; curb[t] = 0; }
  __syncthreads();
  int lo = blockIdx.x * PCH;

  for (int e = lo + t; e < lo + PCH; e += 256)
    atomicAdd(&hist[edge_at(ei, is64, EE + e) >> BSH2], 1);
  __syncthreads();

  if (t < 128) sc[t] = hist[t];
  __syncthreads();
  for (int o = 1; o < 128; o <<= 1) {
    int v = (t >= o && t < 128) ? sc[t - o] : 0;
    __syncthreads();
    if (t < 128) sc[t] += v;
    __syncthreads();
  }
  if (t < 128) offb[t] = sc[t] - hist[t];
  __syncthreads();

  for (int e = lo + t; e < lo + PCH; e += 256) {
    int s = edge_at(ei, is64, e);
    int d = edge_at(ei, is64, EE + e);
    int b = d >> BSH2;
    u32 v = (u32)s | ((u32)(d & 511) << 16) | ((u32)b << 25);
    int p = atomicAdd(&curb[b], 1);
    lbuf[offb[b] + p] = v;
  }
  __syncthreads();

  if (t < 128) {
    int c = hist[t];
    gbase[t] = c ? atomicAdd(&gcnt[t], c) : 0;
  }
  __syncthreads();

  for (int i = t; i < PCH; i += 256) {
    u32 v = lbuf[i];
    int b = v >> 25;
    int pos = gbase[b] + (i - offb[b]);
    if (pos < CAPB) buf[(size_t)b * CAPB + pos] = v;
  }
}

// ---- pass 2: exclusive scan of bucket counts -----------------------------
__global__ void k_scanb(const int* gcnt, int* csrbase, int* rowp) {
  __shared__ int sc[128];
  int t = threadIdx.x;
  int c = (t < NBC) ? min(gcnt[t], CAPB) : 0;
  sc[t] = c;
  __syncthreads();
  for (int o = 1; o < 128; o <<= 1) {
    int v = (t >= o) ? sc[t - o] : 0;
    __syncthreads();
    sc[t] += v;
    __syncthreads();
  }
  if (t < NBC) csrbase[t] = sc[t] - c;
  if (t == 127) rowp[NN] = sc[127];
}

// ---- pass 3: per-bucket local sort -> rowp, dinv, csr --------------------
__global__ void k_csr2(const u32* __restrict__ buf, const int* __restrict__ gcnt,
                       const int* __restrict__ csrbase, int* __restrict__ rowp,
                       float* __restrict__ dinv, int* __restrict__ csr) {
  __shared__ int hist[512], offs[512], cur[512], sc[256];
  int b = blockIdx.x;
  int t = threadIdx.x;
  int cnt = min(gcnt[b], CAPB);
  const u32* mb = buf + (size_t)b * CAPB;
  int cbase = csrbase[b];
  int nbase = b << BSH2;
  int nn = min(512, NN - nbase);
  hist[t] = 0; hist[t + 256] = 0; cur[t] = 0; cur[t + 256] = 0;
  __syncthreads();
  for (int i = t; i < cnt; i += 256) atomicAdd(&hist[(mb[i] >> 16) & 511], 1);
  __syncthreads();
  int a0 = hist[2 * t], a1 = hist[2 * t + 1];
  sc[t] = a0 + a1;
  __syncthreads();
  for (int o = 1; o < 256; o <<= 1) {
    int v = (t >= o) ? sc[t - o] : 0;
    __syncthreads();
    sc[t] += v;
    __syncthreads();
  }
  int excl = sc[t] - (a0 + a1);
  offs[2 * t] = excl; offs[2 * t + 1] = excl + a0;
  __syncthreads();
  for (int i = t; i < nn; i += 256) {
    rowp[nbase + i] = cbase + offs[i];
    dinv[nbase + i] = rsqrtf((float)(hist[i] + 1));
  }
  for (int i = t; i < cnt; i += 256) {
    u32 v = mb[i];
    int dl = (v >> 16) & 511;
    int p = atomicAdd(&cur[dl], 1);
    csr[cbase + offs[dl] + p] = (int)(v & 0xFFFF);
  }
}

// ---- MFMA GEMM (as round 8) ----------------------------------------------
template <int K, int N, bool SRCF32, bool ATT, int NTH>
__global__ void k_mm(const void* __restrict__ Xsrc, const float* __restrict__ W,
                     const float* __restrict__ aw_s, const float* __restrict__ aw_d,
                     u16* __restrict__ Y, float* __restrict__ a_sv,
                     float* __restrict__ a_dv) {
  constexpr int BM = 64;
  constexpr int NT = N / 16;
  constexpr int KS = K / 32;
  __shared__ u16 Ab[BM * K];
  __shared__ u16 Wt[N * K];
  int t = threadIdx.x;
  int blockRow = blockIdx.x * BM;

  if (SRCF32) {
    const float4* Xq = (const float4*)Xsrc + (size_t)blockRow * (K / 4);
    for (int i = t; i < BM * K / 4; i += 256) {
      int r = (i * 4) / K;
      float4 v = (blockRow + r < NN) ? Xq[i] : make_float4(0.f, 0.f, 0.f, 0.f);
      ushort4 p = make_ushort4(f2bf(v.x), f2bf(v.y), f2bf(v.z), f2bf(v.w));
      int b = i * 8;
      *(ushort4*)((char*)Ab + (b ^ ((r & 7) << 4))) = p;
    }
  } else {
    const int4* Xq = (const int4*)Xsrc + (size_t)blockRow * (K / 8);
    for (int i = t; i < BM * K / 8; i += 256) {
      int r = (i * 8) / K;
      int4 v = (blockRow + r < NN) ? Xq[i] : make_int4(0, 0, 0, 0);
      int b = i * 16;
      *(int4*)((char*)Ab + (b ^ ((r & 7) << 4))) = v;
    }
  }
  for (int i = t; i < K * N; i += 256) {
    int k = i / N, n = i % N;
    int b = (n * K + k) * 2;
    *(u16*)((char*)Wt + (b ^ ((n & 7) << 4))) = f2bf(W[i]);
  }
  __syncthreads();

  int w = t >> 6, l = t & 63;
  int lr = l & 15, lg = l >> 4;
  int sw = (lr & 7) << 4;
  f32x4 acc[NT];
#pragma unroll
  for (int nt = 0; nt < NT; ++nt) acc[nt] = (f32x4)0.f;

#pragma unroll
  for (int ks = 0; ks < KS; ++ks) {
    int ar = 16 * w + lr;
    int ab = (ar * K + ks * 32 + lg * 8) * 2;
    bf16x8 af = *(bf16x8*)((char*)Ab + (ab ^ sw));
#pragma unroll
    for (int nt = 0; nt < NT; ++nt) {
      int bb = ((nt * 16 + lr) * K + ks * 32 + lg * 8) * 2;
      bf16x8 bfr = *(bf16x8*)((char*)Wt + (bb ^ sw));
      acc[nt] = __builtin_amdgcn_mfma_f32_16x16x32_bf16(af, bfr, acc[nt], 0, 0, 0);
    }
  }

#pragma unroll
  for (int j = 0; j < 4; ++j) {
    int row = blockRow + 16 * w + lg * 4 + j;
    if (row < NN) {
      u16* yr = Y + (size_t)row * N + lr;
#pragma unroll
      for (int nt = 0; nt < NT; ++nt) yr[nt * 16] = f2bf(acc[nt][j]);
    }
  }

  if (ATT) {
    float aws[NT], awd[NT];
#pragma unroll
    for (int nt = 0; nt < NT; ++nt) {
      aws[nt] = aw_s[nt * 16 + lr];
      awd[nt] = aw_d[nt * 16 + lr];
    }
#pragma unroll
    for (int j = 0; j < 4; ++j) {
      int row = blockRow + 16 * w + lg * 4 + j;
#pragma unroll
      for (int h = 0; h < 2; ++h) {
        float s = 0.f, d = 0.f;
#pragma unroll
        for (int q = 0; q < NTH; ++q) {
          int nt = h * NTH + q;
          s += acc[nt][j] * aws[nt];
          d += acc[nt][j] * awd[nt];
        }
#pragma unroll
        for (int mm = 8; mm >= 1; mm >>= 1) {
          s += __shfl_xor(s, mm, 64);
          d += __shfl_xor(d, mm, 64);
        }
        if (lr == 0 && row < NN) {
          a_sv[row * 2 + h] = s;
          a_dv[row * 2 + h] = d;
        }
      }
    }
  }
}

// ---- GCN aggregation: 4 nodes/wave (16-lane quads); 16 nodes/block -------
__global__ void k_gcn(const u16* __restrict__ g, const float* __restrict__ dinv,
                      const int* __restrict__ rowp, const int* __restrict__ csr,
                      const float* __restrict__ bias, u16* __restrict__ outb) {
  __shared__ int   s_src[16][CAP];
  __shared__ float s_wt[16][CAP];
  int w = (threadIdx.x >> 6) & 3;
  int lane = threadIdx.x & 63;
  int qd = lane >> 4, ql = lane & 15;
  int node = (blockIdx.x * 4 + w) * 4 + qd;     // 3125*16 == 50000 exact
  int ns = w * 4 + qd;
  float di = dinv[node];
  int beg = rowp[node], cnt = rowp[node + 1] - beg;
  int tot = cnt + 1;                             // self loop at idx == cnt
  int c1 = min(tot, CAP);
  int c1p = (c1 + 1) & ~1;                       // pad to 2 (sub-group multiple)

  for (int idx = ql; idx < c1p; idx += 16) {
    int s; float wt;
    if (idx < cnt)      { s = csr[beg + idx]; wt = dinv[s]; }
    else if (idx < tot) { s = node; wt = di; }
    else                { s = node; wt = 0.f; }
    s_src[ns][idx] = s; s_wt[ns][idx] = wt;
  }

  int sg = ql >> 3, q = ql & 7;
  const int4* g4 = (const int4*)g;               // 8 int4 per 64-feature row
  float acc[8] = {0.f, 0.f, 0.f, 0.f, 0.f, 0.f, 0.f, 0.f};
  int nsteps = c1p >> 1;
  int s0 = s_src[ns][sg]; float a0 = s_wt[ns][sg];
  int4 v0 = g4[(size_t)s0 * 8 + q];
  for (int p = 1; p < nsteps; ++p) {
    int i1 = sg + 2 * p;
    int s1 = s_src[ns][i1]; float a1 = s_wt[ns][i1];
    int4 v1 = g4[(size_t)s1 * 8 + q];
    fma8(acc, v0, a0);
    v0 = v1; a0 = a1;
  }
  fma8(acc, v0, a0);
  for (int idx = CAP + sg; idx < tot; idx += 2) {   // essentially never
    int s = (idx < cnt) ? csr[beg + idx] : node;
    float a = (idx < cnt) ? dinv[s] : di;
    fma8(acc, g4[(size_t)s * 8 + q], a);
  }
#pragma unroll
  for (int j = 0; j < 8; ++j) acc[j] += __shfl_xor(acc[j], 8, 64);
  if (sg == 0) {                                  // 8 lanes write the 128B row
    u32 o[4];
#pragma unroll
    for (int p = 0; p < 4; ++p) {
      float v0f = fmaxf(acc[2 * p] * di + bias[8 * q + 2 * p], 0.f);
      float v1f = fmaxf(acc[2 * p + 1] * di + bias[8 * q + 2 * p + 1], 0.f);
      o[p] = pack2bf(v0f, v1f);
    }
    ((int4*)outb)[(size_t)node * 8 + q] = *(int4*)o;
  }
}

// ---- GAT layer 1: 2 nodes/wave (32-lane halves); 8 nodes/block -----------
__global__ void k_gat1(const u16* __restrict__ hg, const float* __restrict__ a_s,
                       const float* __restrict__ a_d, const int* __restrict__ rowp,
                       const int* __restrict__ csr, const float* __restrict__ bias,
                       u16* __restrict__ outb) {
  __shared__ int   s_src[8][CAP];
  __shared__ float s_x[8][CAP][2];
  int w = (threadIdx.x >> 6) & 3;
  int lane = threadIdx.x & 63;
  int hf = lane >> 5, hl = lane & 31;
  int node = (blockIdx.x * 4 + w) * 2 + hf;      // 6250*8 == 50000 exact
  int ns = w * 2 + hf;
  int beg = rowp[node], cnt = rowp[node + 1] - beg;
  int tot = cnt + 1;
  int c1 = min(tot, CAP);
  int c1p = (c1 + 1) & ~1;
  float ad0 = a_d[node * 2], ad1 = a_d[node * 2 + 1];

  // phase 1: stash e, track max (32-lane)
  float mm0 = -1e30f, mm1 = -1e30f;
  for (int idx = hl; idx < c1p; idx += 32) {
    int s = (idx < cnt) ? csr[beg + idx] : node;
    float e0 = -1e30f, e1 = -1e30f;
    if (idx < tot) {
      float2 av = ((const float2*)a_s)[s];
      e0 = av.x + ad0; e0 = e0 > 0.f ? e0 : NEG * e0;
      e1 = av.y + ad1; e1 = e1 > 0.f ? e1 : NEG * e1;
    }
    s_src[ns][idx] = s; s_x[ns][idx][0] = e0; s_x[ns][idx][1] = e1;
    mm0 = fmaxf(mm0, e0); mm1 = fmaxf(mm1, e1);
  }
  for (int idx = CAP + hl; idx < tot; idx += 32) {  // essentially never
    int s = (idx < cnt) ? csr[beg + idx] : node;
    float2 av = ((const float2*)a_s)[s];
    float e0 = av.x + ad0; e0 = e0 > 0.f ? e0 : NEG * e0;
    float e1 = av.y + ad1; e1 = e1 > 0.f ? e1 : NEG * e1;
    mm0 = fmaxf(mm0, e0); mm1 = fmaxf(mm1, e1);
  }
#pragma unroll
  for (int m = 16; m >= 1; m >>= 1) {
    mm0 = fmaxf(mm0, __shfl_xor(mm0, m, 64));
    mm1 = fmaxf(mm1, __shfl_xor(mm1, m, 64));
  }
  // phase 2: exp + sum
  float ss0 = 0.f, ss1 = 0.f;
  for (int idx = hl; idx < c1p; idx += 32) {
    float x0 = __expf(s_x[ns][idx][0] - mm0), x1 = __expf(s_x[ns][idx][1] - mm1);
    s_x[ns][idx][0] = x0; s_x[ns][idx][1] = x1;
    ss0 += x0; ss1 += x1;
  }
  for (int idx = CAP + hl; idx < tot; idx += 32) {
    int s = (idx < cnt) ? csr[beg + idx] : node;
    float2 av = ((const float2*)a_s)[s];
    float e0 = av.x + ad0; e0 = e0 > 0.f ? e0 : NEG * e0;
    float e1 = av.y + ad1; e1 = e1 > 0.f ? e1 : NEG * e1;
    ss0 += __expf(e0 - mm0); ss1 += __expf(e1 - mm1);
  }
#pragma unroll
  for (int m = 16; m >= 1; m >>= 1) {
    ss0 += __shfl_xor(ss0, m, 64);
    ss1 += __shfl_xor(ss1, m, 64);
  }
  float inv0 = 1.f / ss0, inv1 = 1.f / ss1;

  // gather: 16 lanes/row, 2 edges per pass per half
  int sg = hl >> 4, q = hl & 15;
  int hh = q >> 3;                                // head of this dword slice
  const int4* g4 = (const int4*)hg;               // 16 int4 per 128-feature row
  float acc[8] = {0.f, 0.f, 0.f, 0.f, 0.f, 0.f, 0.f, 0.f};
  int nsteps = c1p >> 1;
  int s0 = s_src[ns][sg]; float a0 = s_x[ns][sg][hh];
  int4 v0 = g4[(size_t)s0 * 16 + q];
  for (int p = 1; p < nsteps; ++p) {
    int i1 = sg + 2 * p;
    int s1 = s_src[ns][i1]; float a1 = s_x[ns][i1][hh];
    int4 v1 = g4[(size_t)s1 * 16 + q];
    fma8(acc, v0, a0);
    v0 = v1; a0 = a1;
  }
  fma8(acc, v0, a0);
  for (int idx = CAP + sg; idx < tot; idx += 2) {   // essentially never
    int s = (idx < cnt) ? csr[beg + idx] : node;
    float e = (hh ? a_s[s * 2 + 1] + ad1 : a_s[s * 2] + ad0);
    e = e > 0.f ? e : NEG * e;
    float a = __expf(e - (hh ? mm1 : mm0));
    fma8(acc, g4[(size_t)s * 16 + q], a);
  }
#pragma unroll
  for (int j = 0; j < 8; ++j) acc[j] += __shfl_xor(acc[j], 16, 64);
  if (sg == 0) {                                  // 16 lanes write the 256B row
    float invh = hh ? inv1 : inv0;
    u32 o[4];
#pragma unroll
    for (int p = 0; p < 4; ++p) {
      float v0f = fmaxf(acc[2 * p] * invh + bias[8 * q + 2 * p], 0.f);
      float v1f = fmaxf(acc[2 * p + 1] * invh + bias[8 * q + 2 * p + 1], 0.f);
      o[p] = pack2bf(v0f, v1f);
    }
    ((int4*)outb)[(size_t)node * 16 + q] = *(int4*)o;
  }
}

// ---- GAT layer 2: 4 nodes/wave (16-lane quads); head-mean + lsm ----------
__global__ void k_gat2(const u16* __restrict__ hg, const float* __restrict__ a_s,
                       const float* __restrict__ a_d, const int* __restrict__ rowp,
                       const int* __restrict__ csr, const float* __restrict__ bias,
                       float* __restrict__ out) {
  __shared__ int   s_src[16][CAP];
  __shared__ float s_x[16][CAP][2];
  int w = (threadIdx.x >> 6) & 3;
  int lane = threadIdx.x & 63;
  int qd = lane >> 4, ql = lane & 15;
  int node = (blockIdx.x * 4 + w) * 4 + qd;
  int ns = w * 4 + qd;
  int beg = rowp[node], cnt = rowp[node + 1] - beg;
  int tot = cnt + 1;
  int c1 = min(tot, CAP);
  int c1p = (c1 + 1) & ~1;
  float ad0 = a_d[node * 2], ad1 = a_d[node * 2 + 1];

  // phase 1: stash e, track max (16-lane)
  float mm0 = -1e30f, mm1 = -1e30f;
  for (int idx = ql; idx < c1p; idx += 16) {
    int s = (idx < cnt) ? csr[beg + idx] : node;
    float e0 = -1e30f, e1 = -1e30f;
    if (idx < tot) {
      float2 av = ((const float2*)a_s)[s];
      e0 = av.x + ad0; e0 = e0 > 0.f ? e0 : NEG * e0;
      e1 = av.y + ad1; e1 = e1 > 0.f ? e1 : NEG * e1;
    }
    s_src[ns][idx] = s; s_x[ns][idx][0] = e0; s_x[ns][idx][1] = e1;
    mm0 = fmaxf(mm0, e0); mm1 = fmaxf(mm1, e1);
  }
  for (int idx = CAP + ql; idx < tot; idx += 16) {  // essentially never
    int s = (idx < cnt) ? csr[beg + idx] : node;
    float2 av = ((const float2*)a_s)[s];
    float e0 = av.x + ad0; e0 = e0 > 0.f ? e0 : NEG * e0;
    float e1 = av.y + ad1; e1 = e1 > 0.f ? e1 : NEG * e1;
    mm0 = fmaxf(mm0, e0); mm1 = fmaxf(mm1, e1);
  }
#pragma unroll
  for (int m = 8; m >= 1; m >>= 1) {
    mm0 = fmaxf(mm0, __shfl_xor(mm0, m, 64));
    mm1 = fmaxf(mm1, __shfl_xor(mm1, m, 64));
  }
  // phase 2: exp + sum
  float ss0 = 0.f, ss1 = 0.f;
  for (int idx = ql; idx < c1p; idx += 16) {
    float x0 = __expf(s_x[ns][idx][0] - mm0), x1 = __expf(s_x[ns][idx][1] - mm1);
    s_x[ns][idx][0] = x0; s_x[ns][idx][1] = x1;
    ss0 += x0; ss1 += x1;
  }
  for (int idx = CAP + ql; idx < tot; idx += 16) {
    int s = (idx < cnt) ? csr[beg + idx] : node;
    float2 av = ((const float2*)a_s)[s];
    float e0 = av.x + ad0; e0 = e0 > 0.f ? e0 : NEG * e0;
    float e1 = av.y + ad1; e1 = e1 > 0.f ? e1 : NEG * e1;
    ss0 += __expf(e0 - mm0); ss1 += __expf(e1 - mm1);
  }
#pragma unroll
  for (int m = 8; m >= 1; m >>= 1) {
    ss0 += __shfl_xor(ss0, m, 64);
    ss1 += __shfl_xor(ss1, m, 64);
  }
  float inv0 = 1.f / ss0, inv1 = 1.f / ss1;

  // gather: 8 lanes/row, 2 edges per pass per quad
  int sg = ql >> 3, q = ql & 7;
  int hh = q >> 2;                               // head of this dword slice
  const int4* g4 = (const int4*)hg;              // 8 int4 per 64-feature row
  float acc[8] = {0.f, 0.f, 0.f, 0.f, 0.f, 0.f, 0.f, 0.f};
  int nsteps = c1p >> 1;
  int s0 = s_src[ns][sg]; float a0 = s_x[ns][sg][hh];
  int4 v0 = g4[(size_t)s0 * 8 + q];
  for (int p = 1; p < nsteps; ++p) {
    int i1 = sg + 2 * p;
    int s1 = s_src[ns][i1]; float a1 = s_x[ns][i1][hh];
    int4 v1 = g4[(size_t)s1 * 8 + q];
    fma8(acc, v0, a0);
    v0 = v1; a0 = a1;
  }
  fma8(acc, v0, a0);
  for (int idx = CAP + sg; idx < tot; idx += 2) {   // essentially never
    int s = (idx < cnt) ? csr[beg + idx] : node;
    float e = (hh ? a_s[s * 2 + 1] + ad1 : a_s[s * 2] + ad0);
    e = e > 0.f ? e : NEG * e;
    float a = __expf(e - (hh ? mm1 : mm0));
    fma8(acc, g4[(size_t)s * 8 + q], a);
  }
#pragma unroll
  for (int j = 0; j < 8; ++j) acc[j] += __shfl_xor(acc[j], 8, 64);

  // normalize, head-mean (partner dword q^4 = other head, same channels)
  float invh = hh ? inv1 : inv0;
  float vv[8];
#pragma unroll
  for (int j = 0; j < 8; ++j) {
    float a = acc[j] * invh;
    vv[j] = 0.5f * (a + __shfl_xor(a, 4, 64)) + bias[8 * (q & 3) + j];
  }
  // log_softmax over 32 classes held by lanes q in {0..3} (dup on q>=4, sg=1)
  float mx = vv[0];
#pragma unroll
  for (int j = 1; j < 8; ++j) mx = fmaxf(mx, vv[j]);
  mx = fmaxf(mx, __shfl_xor(mx, 1, 64));
  mx = fmaxf(mx, __shfl_xor(mx, 2, 64));
  float se = 0.f;
#pragma unroll
  for (int j = 0; j < 8; ++j) se += __expf(vv[j] - mx);
  se += __shfl_xor(se, 1, 64);
  se += __shfl_xor(se, 2, 64);
  float lse = mx + __logf(se);
  if (ql < 4) {                                  // lanes 0..3 of quad write row
    float4 o0 = make_float4(vv[0] - lse, vv[1] - lse, vv[2] - lse, vv[3] - lse);
    float4 o1 = make_float4(vv[4] - lse, vv[5] - lse, vv[6] - lse, vv[7] - lse);
    float4* orow = (float4*)(out + (size_t)node * 32);
    orow[q * 2] = o0;
    orow[q * 2 + 1] = o1;
  }
}

// --------------------------------------------------------------------------
extern "C" void kernel_launch(void* const* d_in, const int* in_sizes, int n_in,
                              void* d_out, int out_size, void* d_ws, size_t ws_size,
                              hipStream_t stream) {
  (void)in_sizes; (void)n_in; (void)out_size; (void)ws_size;
  const float* x   = (const float*)d_in[0];
  const void*  ei  = d_in[1];
  const float* W1  = (const float*)d_in[2];
  const float* b1  = (const float*)d_in[3];
  const float* W2  = (const float*)d_in[4];
  const float* b2  = (const float*)d_in[5];
  const float* Wg1 = (const float*)d_in[6];
  const float* as1 = (const float*)d_in[7];
  const float* ad1 = (const float*)d_in[8];
  const float* bg1 = (const float*)d_in[9];
  const float* Wg2 = (const float*)d_in[10];
  const float* as2 = (const float*)d_in[11];
  const float* ad2 = (const float*)d_in[12];
  const float* bg2 = (const float*)d_in[13];
  float* out = (float*)d_out;

  char* w = (char*)d_ws;
  auto alloc = [&](size_t bytes) { char* p = w; w += (bytes + 255) & ~(size_t)255; return p; };
  u16* Hb     = (u16*)alloc((size_t)NN * 128 * 2);   // GEMM outputs (bf16)
  u16* Xb     = (u16*)alloc((size_t)NN * 128 * 2);   // aggregation outputs (bf16)
  float* dinv = (float*)alloc((size_t)NN * 4);
  float* asb  = (float*)alloc((size_t)NN * 2 * 4);
  float* adb  = (float*)alloc((size_t)NN * 2 * 4);
  int* rowp   = (int*)alloc((size_t)(NN + 1) * 4);
  int* csr    = (int*)alloc((size_t)EE * 4);
  u32* buf    = (u32*)alloc((size_t)NBC * CAPB * 4);
  int* gcnt   = (int*)alloc((size_t)NBC * 4);
  int* csrbase= (int*)alloc((size_t)NBC * 4);
  int* flag   = (int*)alloc(16);

  const int TB = 256;
  int gQ = 3125;                    // 16 nodes/block (k_gcn, k_gat2)
  int gH = 6250;                    // 8 nodes/block (k_gat1)
  int gG = (NN + 63) / 64;          // 64-row GEMM blocks

  // CSR build (two-pass radix partition)
  k_probe<<<1, 256, 0, stream>>>(ei, flag, gcnt);
  k_part<<<256, TB, 0, stream>>>(ei, flag, gcnt, buf);
  k_scanb<<<1, 128, 0, stream>>>(gcnt, csrbase, rowp);
  k_csr2<<<NBC, TB, 0, stream>>>(buf, gcnt, csrbase, rowp, dinv, csr);

  // GCN 1
  k_mm<128, 64, true, false, 0><<<gG, TB, 0, stream>>>(x, W1, nullptr, nullptr, Hb, nullptr, nullptr);
  k_gcn<<<gQ, TB, 0, stream>>>(Hb, dinv, rowp, csr, b1, Xb);
  // GCN 2
  k_mm<64, 64, false, false, 0><<<gG, TB, 0, stream>>>(Xb, W2, nullptr, nullptr, Hb, nullptr, nullptr);
  k_gcn<<<gQ, TB, 0, stream>>>(Hb, dinv, rowp, csr, b2, Xb);
  // GAT 1 (concat, relu) + fused att coefficients
  k_mm<64, 128, false, true, 4><<<gG, TB, 0, stream>>>(Xb, Wg1, as1, ad1, Hb, asb, adb);
  k_gat1<<<gH, TB, 0, stream>>>(Hb, asb, adb, rowp, csr, bg1, Xb);
  // GAT 2 (head mean) + log_softmax, fused att coefficients
  k_mm<128, 64, false, true, 2><<<gG, TB, 0, stream>>>(Xb, Wg2, as2, ad2, Hb, asb, adb);
  k_gat2<<<gQ, TB, 0, stream>>>(Hb, asb, adb, rowp, csr, bg2, out);
}